// Round 8
// baseline (350.515 us; speedup 1.0000x reference)
//
#include <hip/hip_runtime.h>
#include <hip/hip_bf16.h>

#define N_NODES 50000
#define M_PAD 50048
#define N_EDGES 400000
#define SCAN_B 256

typedef __attribute__((ext_vector_type(8))) short short8;
typedef __attribute__((ext_vector_type(4))) float f32x4;

__device__ __forceinline__ unsigned short f2b(float f) {
    unsigned u = __float_as_uint(f);
    return (unsigned short)((u + 0x7fffu + ((u >> 16) & 1u)) >> 16);
}
__device__ __forceinline__ float blo(unsigned u) { return __uint_as_float(u << 16); }
__device__ __forceinline__ float bhi(unsigned u) { return __uint_as_float(u & 0xffff0000u); }

__device__ __forceinline__ void gload_lds16(const void* g, void* l) {
    __builtin_amdgcn_global_load_lds(
        (const __attribute__((address_space(1))) unsigned int*)g,
        (__attribute__((address_space(3))) unsigned int*)l, 16, 0, 0);
}

// ---------------- fused prep: x->bf16, weights->bf16 transposed, degree histogram ----------------
#define X4_N (N_NODES * 64)
#define W1_SZ (512 * 256)
#define W2_SZ (512 * 512)
#define W3_SZ (64 * 512)
#define WTOT (W1_SZ + W2_SZ + 2 * W3_SZ)
__global__ __launch_bounds__(256) void prep_k(const float* __restrict__ x,
                                              const float* __restrict__ W1,
                                              const float* __restrict__ W2,
                                              const float* __restrict__ W3,
                                              const float* __restrict__ Wr3,
                                              const int* __restrict__ dst,
                                              unsigned short* __restrict__ xb,
                                              unsigned short* __restrict__ Wt1,
                                              unsigned short* __restrict__ Wt2,
                                              unsigned short* __restrict__ Wt3,
                                              int* __restrict__ deg) {
    int i = blockIdx.x * blockDim.x + threadIdx.x;
    if (i < X4_N) {
        float4 v = *(const float4*)&x[(size_t)i * 4];
        unsigned short o[4] = {f2b(v.x), f2b(v.y), f2b(v.z), f2b(v.w)};
        *(ushort2*)&xb[(size_t)i * 4] = make_ushort2(o[0], o[1]);
        *(ushort2*)&xb[(size_t)i * 4 + 2] = make_ushort2(o[2], o[3]);
        return;
    }
    int o = i - X4_N;
    if (o < W1_SZ) {
        int n = o / 256, k = o % 256;
        Wt1[o] = f2b(W1[(size_t)k * 512 + n]);
    } else if (o < W1_SZ + W2_SZ) {
        int oo = o - W1_SZ;
        int n = oo / 512, k = oo % 512;
        Wt2[oo] = f2b(W2[(size_t)k * 512 + n]);
    } else if (o < W1_SZ + W2_SZ + W3_SZ) {
        int oo = o - W1_SZ - W2_SZ;
        int n = oo / 512, k = oo % 512;
        Wt3[oo] = f2b(W3[(size_t)k * 64 + n]);
    } else if (o < WTOT) {
        int oo = o - W1_SZ - W2_SZ - W3_SZ;
        int n = oo / 512, k = oo % 512;
        Wt3[W3_SZ + oo] = f2b(Wr3[(size_t)k * 64 + n]);
    } else {
        int e = o - WTOT;
        if (e < N_EDGES) atomicAdd(&deg[dst[e]], 1);
    }
}

// ---------------- 128x256 bf16 MFMA GEMM (layers 1/2), 8 waves, fused el/er ----------------
// Grid: 8*chunk blocks; XCD x owns consecutive tiles t = x*chunk+q -> A-panel L2 reuse.
template <int H>
__global__ __launch_bounds__(512) void gemm256(const unsigned short* __restrict__ A,
                                               const unsigned short* __restrict__ Bt,
                                               unsigned short* __restrict__ C,
                                               const float* __restrict__ al,
                                               const float* __restrict__ ar,
                                               float* __restrict__ el,
                                               float* __restrict__ er,
                                               int M, int NN, int K) {
    const int nby = (M + 127) >> 7;
    const int tiles = nby * 2;
    const int chunk = (tiles + 7) >> 3;
    const int x = blockIdx.x & 7, q = blockIdx.x >> 3;
    const int t = x * chunk + q;
    if (t >= tiles) return;
    const int r = t >> 1, c = t & 1;
    __shared__ unsigned short As[128 * 32];
    __shared__ unsigned short Bs[256 * 32];
    const int tid = threadIdx.x;
    const int w = tid >> 6, l = tid & 63;
    const int bm = r * 128, bn = c * 256;
    const int wr = w >> 2, wc = w & 3;       // wave grid 2x4 over 128x256
    const int fr = l & 15, fq = l >> 4;
    const int lr = l >> 2, lk = (l & 3) * 8; // staging: lane row/ k-offset
    f32x4 acc[4][4] = {};

    for (int k0 = 0; k0 < K; k0 += 32) {
        // A: wave w stages rows w*16..w*16+15 (LDS dest wave-uniform + lane*16B)
        gload_lds16(&A[(size_t)(bm + w * 16 + lr) * K + k0 + lk], &As[w * 512]);
        // B: 2 passes of 128 rows
        gload_lds16(&Bt[(size_t)(bn + w * 16 + lr) * K + k0 + lk], &Bs[w * 512]);
        gload_lds16(&Bt[(size_t)(bn + 128 + w * 16 + lr) * K + k0 + lk], &Bs[4096 + w * 512]);
        __syncthreads();
        short8 a[4], b[4];
#pragma unroll
        for (int m = 0; m < 4; ++m)
            a[m] = *(const short8*)&As[(wr * 64 + m * 16 + fr) * 32 + fq * 8];
#pragma unroll
        for (int n = 0; n < 4; ++n)
            b[n] = *(const short8*)&Bs[(wc * 64 + n * 16 + fr) * 32 + fq * 8];
#pragma unroll
        for (int m = 0; m < 4; ++m)
#pragma unroll
            for (int n = 0; n < 4; ++n)
                acc[m][n] = __builtin_amdgcn_mfma_f32_16x16x32_bf16(a[m], b[n], acc[m][n], 0, 0, 0);
        __syncthreads();
    }

    // fused el/er: wave's 64-col strip = head (bn + wc*64)/64
    {
        const int head = (bn >> 6) + wc;
        if (head < H) {
            float alv[4], arv[4];
#pragma unroll
            for (int n = 0; n < 4; ++n) {
                alv[n] = al[head * 64 + n * 16 + fr];
                arv[n] = ar[head * 64 + n * 16 + fr];
            }
#pragma unroll
            for (int m = 0; m < 4; ++m) {
#pragma unroll
                for (int j = 0; j < 4; ++j) {
                    float pl = acc[m][0][j] * alv[0] + acc[m][1][j] * alv[1] +
                               acc[m][2][j] * alv[2] + acc[m][3][j] * alv[3];
                    float pr = acc[m][0][j] * arv[0] + acc[m][1][j] * arv[1] +
                               acc[m][2][j] * arv[2] + acc[m][3][j] * arv[3];
#pragma unroll
                    for (int off = 1; off < 16; off <<= 1) {
                        pl += __shfl_xor(pl, off);
                        pr += __shfl_xor(pr, off);
                    }
                    int rr = bm + wr * 64 + m * 16 + fq * 4 + j;
                    if (fr == 0 && rr < M) {
                        el[(size_t)rr * H + head] = pl;
                        er[(size_t)rr * H + head] = pr;
                    }
                }
            }
        }
    }

#pragma unroll
    for (int m = 0; m < 4; ++m) {
#pragma unroll
        for (int j = 0; j < 4; ++j) {
            int rr = bm + wr * 64 + m * 16 + fq * 4 + j;
            if (rr < M) {
#pragma unroll
                for (int n = 0; n < 4; ++n)
                    C[(size_t)rr * NN + bn + wc * 64 + n * 16 + fr] = f2b(acc[m][n][j]);
            }
        }
    }
}

// ---------------- 128x128 bf16 MFMA GEMM (layer 3), fused el/er ----------------
template <int H>
__global__ __launch_bounds__(256, 2) void gemm_mfma(const unsigned short* __restrict__ A,
                                                    const unsigned short* __restrict__ Bt,
                                                    unsigned short* __restrict__ C,
                                                    const float* __restrict__ al,
                                                    const float* __restrict__ ar,
                                                    float* __restrict__ el,
                                                    float* __restrict__ er,
                                                    int M, int NN, int K) {
    int r = blockIdx.x, c = 0;
    __shared__ unsigned short As[128 * 32];
    __shared__ unsigned short Bs[128 * 32];
    const int tid = threadIdx.x;
    const int w = tid >> 6, l = tid & 63;
    const int bm = r * 128, bn = c * 128;
    const int wr = w >> 1, wc = w & 1;
    const int rA = l >> 2;
    const int kA = (l & 3) * 8;
    const int fr = l & 15, fq = l >> 4;
    f32x4 acc[4][4] = {};

    for (int k0 = 0; k0 < K; k0 += 32) {
#pragma unroll
        for (int j = 0; j < 2; ++j) {
            int row = w * 32 + j * 16 + rA;
            gload_lds16(&A[(size_t)(bm + row) * K + k0 + kA], &As[(w * 2 + j) * 512]);
            gload_lds16(&Bt[(size_t)(bn + row) * K + k0 + kA], &Bs[(w * 2 + j) * 512]);
        }
        __syncthreads();
        short8 a[4], b[4];
#pragma unroll
        for (int m = 0; m < 4; ++m)
            a[m] = *(const short8*)&As[(wr * 64 + m * 16 + fr) * 32 + fq * 8];
#pragma unroll
        for (int n = 0; n < 4; ++n)
            b[n] = *(const short8*)&Bs[(wc * 64 + n * 16 + fr) * 32 + fq * 8];
#pragma unroll
        for (int m = 0; m < 4; ++m)
#pragma unroll
            for (int n = 0; n < 4; ++n)
                acc[m][n] = __builtin_amdgcn_mfma_f32_16x16x32_bf16(a[m], b[n], acc[m][n], 0, 0, 0);
        __syncthreads();
    }

    {
        const int head = (bn >> 6) + wc;
        if (head < H) {
            float alv[4], arv[4];
#pragma unroll
            for (int n = 0; n < 4; ++n) {
                alv[n] = al[head * 64 + n * 16 + fr];
                arv[n] = ar[head * 64 + n * 16 + fr];
            }
#pragma unroll
            for (int m = 0; m < 4; ++m) {
#pragma unroll
                for (int j = 0; j < 4; ++j) {
                    float pl = acc[m][0][j] * alv[0] + acc[m][1][j] * alv[1] +
                               acc[m][2][j] * alv[2] + acc[m][3][j] * alv[3];
                    float pr = acc[m][0][j] * arv[0] + acc[m][1][j] * arv[1] +
                               acc[m][2][j] * arv[2] + acc[m][3][j] * arv[3];
#pragma unroll
                    for (int off = 1; off < 16; off <<= 1) {
                        pl += __shfl_xor(pl, off);
                        pr += __shfl_xor(pr, off);
                    }
                    int rr = bm + wr * 64 + m * 16 + fq * 4 + j;
                    if (fr == 0 && rr < M) {
                        el[(size_t)rr * H + head] = pl;
                        er[(size_t)rr * H + head] = pr;
                    }
                }
            }
        }
    }

#pragma unroll
    for (int m = 0; m < 4; ++m) {
#pragma unroll
        for (int j = 0; j < 4; ++j) {
            int rr = bm + wr * 64 + m * 16 + fq * 4 + j;
            if (rr < M) {
#pragma unroll
                for (int n = 0; n < 4; ++n)
                    C[(size_t)rr * NN + bn + wc * 64 + n * 16 + fr] = f2b(acc[m][n][j]);
            }
        }
    }
}

// ---------------- CSR build ----------------
__global__ __launch_bounds__(SCAN_B) void scan_blocks(const int* __restrict__ in,
                                                      int* __restrict__ out,
                                                      int* __restrict__ part, int n) {
    __shared__ int tmp[SCAN_B];
    int t = threadIdx.x, g = blockIdx.x * SCAN_B + t;
    int v = (g < n) ? in[g] : 0;
    tmp[t] = v;
    __syncthreads();
    for (int off = 1; off < SCAN_B; off <<= 1) {
        int add = (t >= off) ? tmp[t - off] : 0;
        __syncthreads();
        tmp[t] += add;
        __syncthreads();
    }
    if (g < n) out[g] = tmp[t] - v;
    if (t == SCAN_B - 1) part[blockIdx.x] = tmp[t];
}

__global__ __launch_bounds__(SCAN_B) void scan_part(int* __restrict__ part, int n) {
    __shared__ int tmp[SCAN_B];
    int t = threadIdx.x;
    int v = (t < n) ? part[t] : 0;
    tmp[t] = v;
    __syncthreads();
    for (int off = 1; off < SCAN_B; off <<= 1) {
        int add = (t >= off) ? tmp[t - off] : 0;
        __syncthreads();
        tmp[t] += add;
        __syncthreads();
    }
    if (t < n) part[t] = tmp[t] - v;
}

__global__ __launch_bounds__(256) void add_off(int* __restrict__ rowptr,
                                               int* __restrict__ cursor,
                                               const int* __restrict__ part,
                                               int* __restrict__ csr_src,
                                               int n, int E) {
    int g = blockIdx.x * blockDim.x + threadIdx.x;
    if (g < n) {
        int v = rowptr[g] + part[g / SCAN_B];
        rowptr[g] = v;
        cursor[g] = v;
    }
    if (g == 0) rowptr[n] = E;
    if (g < 8) csr_src[E + g] = 0;   // pad: valid node id
}

__global__ __launch_bounds__(256) void scatter_k(const int* __restrict__ src,
                                                 const int* __restrict__ dst,
                                                 int* __restrict__ cursor,
                                                 int* __restrict__ csr_src, int E) {
    int e = blockIdx.x * blockDim.x + threadIdx.x;
    if (e < E) {
        int p = atomicAdd(&cursor[dst[e]], 1);
        csr_src[p] = src[e];
    }
}

// ---------------- fused GAT aggregation H=8 ----------------
template <bool HAS_INIT>
__global__ __launch_bounds__(256) void gat_agg8(const unsigned short* __restrict__ f,
                                                const float* __restrict__ el,
                                                const float* __restrict__ er,
                                                const int* __restrict__ rowptr,
                                                const int* __restrict__ csr_src,
                                                const unsigned short* __restrict__ init,
                                                const float* __restrict__ bias,
                                                unsigned short* __restrict__ outb, int N) {
    int w = (blockIdx.x * blockDim.x + threadIdx.x) >> 6;
    int lane = threadIdx.x & 63;
    if (w >= N) return;
    const int d = w;
    const int s0 = rowptr[d], s1 = rowptr[d + 1];
    const int hh = lane & 7;
    const int esub = lane >> 3;
    const int myhead = lane >> 3;
    const int sl8 = lane * 8;
    const float erh = er[(size_t)d * 8 + hh];

    int snj[8];
#pragma unroll
    for (int j = 0; j < 8; ++j)
        snj[j] = csr_src[(s0 + j < s1) ? (s0 + j) : N_EDGES];
    uint4 pk[8];
#pragma unroll
    for (int j = 0; j < 8; ++j)
        pk[j] = *(const uint4*)&f[(size_t)snj[j] * 512 + sl8];

    bool valid0 = s0 + esub < s1;
    float v0 = el[(size_t)snj[esub] * 8 + hh] + erh;
    v0 = v0 > 0.f ? v0 : 0.2f * v0;
    float mx = valid0 ? v0 : -1e30f;
    for (int i = s0 + 8 + esub; i < s1; i += 8) {
        float v = el[(size_t)csr_src[i] * 8 + hh] + erh;
        v = v > 0.f ? v : 0.2f * v;
        mx = fmaxf(mx, v);
    }
    mx = fmaxf(mx, __shfl_xor(mx, 8));
    mx = fmaxf(mx, __shfl_xor(mx, 16));
    mx = fmaxf(mx, __shfl_xor(mx, 32));

    float am0 = valid0 ? __expf(v0 - mx) : 0.f;
    float sm = am0;
    float acc[8] = {};
#pragma unroll
    for (int j = 0; j < 8; ++j) {
        float alpha = __shfl(am0, (j << 3) | myhead);
        acc[0] += blo(pk[j].x) * alpha;
        acc[1] += bhi(pk[j].x) * alpha;
        acc[2] += blo(pk[j].y) * alpha;
        acc[3] += bhi(pk[j].y) * alpha;
        acc[4] += blo(pk[j].z) * alpha;
        acc[5] += bhi(pk[j].z) * alpha;
        acc[6] += blo(pk[j].w) * alpha;
        acc[7] += bhi(pk[j].w) * alpha;
    }

    for (int ii = s0 + 8; ii < s1; ii += 8) {
        int sn2[8];
#pragma unroll
        for (int j = 0; j < 8; ++j)
            sn2[j] = csr_src[(ii + j < s1) ? (ii + j) : N_EDGES];
        uint4 qk[8];
#pragma unroll
        for (int j = 0; j < 8; ++j)
            qk[j] = *(const uint4*)&f[(size_t)sn2[j] * 512 + sl8];
        bool valid = ii + esub < s1;
        float v = el[(size_t)sn2[esub] * 8 + hh] + erh;
        v = v > 0.f ? v : 0.2f * v;
        float am = valid ? __expf(v - mx) : 0.f;
        sm += am;
#pragma unroll
        for (int j = 0; j < 8; ++j) {
            float alpha = __shfl(am, (j << 3) | myhead);
            acc[0] += blo(qk[j].x) * alpha;
            acc[1] += bhi(qk[j].x) * alpha;
            acc[2] += blo(qk[j].y) * alpha;
            acc[3] += bhi(qk[j].y) * alpha;
            acc[4] += blo(qk[j].z) * alpha;
            acc[5] += bhi(qk[j].z) * alpha;
            acc[6] += blo(qk[j].w) * alpha;
            acc[7] += bhi(qk[j].w) * alpha;
        }
    }

    sm += __shfl_xor(sm, 8);
    sm += __shfl_xor(sm, 16);
    sm += __shfl_xor(sm, 32);
    float smh = __shfl(sm, myhead);
    float inv = smh > 0.f ? 1.0f / smh : 0.f;
#pragma unroll
    for (int j = 0; j < 8; ++j) acc[j] *= inv;

    const int sl = (lane & 7) * 8;
    float4 b0 = *(const float4*)&bias[myhead * 64 + sl];
    float4 b1 = *(const float4*)&bias[myhead * 64 + sl + 4];
    float bb[8] = {b0.x, b0.y, b0.z, b0.w, b1.x, b1.y, b1.z, b1.w};
    if (HAS_INIT) {
        uint4 iv = *(const uint4*)&init[(size_t)d * 512 + sl8];
        acc[0] += blo(iv.x); acc[1] += bhi(iv.x);
        acc[2] += blo(iv.y); acc[3] += bhi(iv.y);
        acc[4] += blo(iv.z); acc[5] += bhi(iv.z);
        acc[6] += blo(iv.w); acc[7] += bhi(iv.w);
    }
    unsigned short ob[8];
#pragma unroll
    for (int j = 0; j < 8; ++j) {
        float v = acc[j] + bb[j];
        v = v > 0.f ? v : __expf(v) - 1.f;
        ob[j] = f2b(v);
    }
    uint4 ov;
    ov.x = (unsigned)ob[0] | ((unsigned)ob[1] << 16);
    ov.y = (unsigned)ob[2] | ((unsigned)ob[3] << 16);
    ov.z = (unsigned)ob[4] | ((unsigned)ob[5] << 16);
    ov.w = (unsigned)ob[6] | ((unsigned)ob[7] << 16);
    *(uint4*)&outb[(size_t)d * 512 + sl8] = ov;
}

// ---------------- fused GAT aggregation H=1 (layer 3) ----------------
__global__ __launch_bounds__(256) void gat_agg1(const unsigned short* __restrict__ f, // [*,128]
                                                const float* __restrict__ el,
                                                const float* __restrict__ er,
                                                const int* __restrict__ rowptr,
                                                const int* __restrict__ csr_src,
                                                const float* __restrict__ bias,
                                                float* __restrict__ outf, int N) {
    int w = (blockIdx.x * blockDim.x + threadIdx.x) >> 6;
    int lane = threadIdx.x & 63;
    if (w >= N) return;
    const int d = w;
    const int s0 = rowptr[d], s1 = rowptr[d + 1];
    const int esub = lane >> 3, sl = (lane & 7) * 8;
    const float erh = er[d];

    int snj[8];
#pragma unroll
    for (int j = 0; j < 8; ++j)
        snj[j] = csr_src[(s0 + j < s1) ? (s0 + j) : N_EDGES];
    int sn0 = snj[esub];
    uint4 pk0 = *(const uint4*)&f[(size_t)sn0 * 128 + sl];

    bool valid0 = s0 + esub < s1;
    float v0 = el[sn0] + erh;
    v0 = v0 > 0.f ? v0 : 0.2f * v0;
    float mx = valid0 ? v0 : -1e30f;
    for (int i = s0 + 8 + esub; i < s1; i += 8) {
        float v = el[csr_src[i]] + erh;
        v = v > 0.f ? v : 0.2f * v;
        mx = fmaxf(mx, v);
    }
    mx = fmaxf(mx, __shfl_xor(mx, 8));
    mx = fmaxf(mx, __shfl_xor(mx, 16));
    mx = fmaxf(mx, __shfl_xor(mx, 32));

    float am0 = valid0 ? __expf(v0 - mx) : 0.f;
    float sm = am0;
    float acc[8];
    acc[0] = blo(pk0.x) * am0; acc[1] = bhi(pk0.x) * am0;
    acc[2] = blo(pk0.y) * am0; acc[3] = bhi(pk0.y) * am0;
    acc[4] = blo(pk0.z) * am0; acc[5] = bhi(pk0.z) * am0;
    acc[6] = blo(pk0.w) * am0; acc[7] = bhi(pk0.w) * am0;

    for (int ii = s0 + 8; ii < s1; ii += 8) {
        int i = ii + esub;
        bool valid = i < s1;
        int sn = csr_src[valid ? i : N_EDGES];
        uint4 pk = *(const uint4*)&f[(size_t)sn * 128 + sl];
        float v = el[sn] + erh;
        v = v > 0.f ? v : 0.2f * v;
        float am = valid ? __expf(v - mx) : 0.f;
        sm += am;
        acc[0] += blo(pk.x) * am; acc[1] += bhi(pk.x) * am;
        acc[2] += blo(pk.y) * am; acc[3] += bhi(pk.y) * am;
        acc[4] += blo(pk.z) * am; acc[5] += bhi(pk.z) * am;
        acc[6] += blo(pk.w) * am; acc[7] += bhi(pk.w) * am;
    }

    sm += __shfl_xor(sm, 8);
    sm += __shfl_xor(sm, 16);
    sm += __shfl_xor(sm, 32);
#pragma unroll
    for (int off = 8; off < 64; off <<= 1)
#pragma unroll
        for (int j = 0; j < 8; ++j) acc[j] += __shfl_xor(acc[j], off);
    float inv = sm > 0.f ? 1.0f / sm : 0.f;

    if (esub == 0) {
        uint4 rv = *(const uint4*)&f[(size_t)d * 128 + 64 + sl];
        float rr[8] = {blo(rv.x), bhi(rv.x), blo(rv.y), bhi(rv.y),
                       blo(rv.z), bhi(rv.z), blo(rv.w), bhi(rv.w)};
#pragma unroll
        for (int j = 0; j < 8; ++j)
            outf[(size_t)d * 64 + sl + j] = acc[j] * inv + bias[sl + j] + rr[j];
    }
}

extern "C" void kernel_launch(void* const* d_in, const int* in_sizes, int n_in,
                              void* d_out, int out_size, void* d_ws, size_t ws_size,
                              hipStream_t stream) {
    const float* x   = (const float*)d_in[0];
    const int*   src = (const int*)d_in[1];
    const int*   dst = (const int*)d_in[2];
    const float* W1  = (const float*)d_in[3];
    const float* al1 = (const float*)d_in[4];
    const float* ar1 = (const float*)d_in[5];
    const float* b1  = (const float*)d_in[6];
    const float* W2  = (const float*)d_in[7];
    const float* al2 = (const float*)d_in[8];
    const float* ar2 = (const float*)d_in[9];
    const float* b2  = (const float*)d_in[10];
    const float* W3  = (const float*)d_in[11];
    const float* al3 = (const float*)d_in[12];
    const float* ar3 = (const float*)d_in[13];
    const float* b3  = (const float*)d_in[14];
    const float* Wr3 = (const float*)d_in[15];
    float* out = (float*)d_out;

    unsigned short* xb   = (unsigned short*)d_ws;               // [M_PAD][256]
    unsigned short* fb   = xb + (size_t)M_PAD * 256;            // [M_PAD][512]
    unsigned short* h1b  = fb + (size_t)M_PAD * 512;            // [M_PAD][512]
    unsigned short* h2b  = h1b + (size_t)M_PAD * 512;           // [M_PAD][512]
    unsigned short* f3r  = h2b + (size_t)M_PAD * 512;           // [M_PAD][128]
    unsigned short* Wt1  = f3r + (size_t)M_PAD * 128;           // [512][256]
    unsigned short* Wt2  = Wt1 + 512 * 256;                     // [512][512]
    unsigned short* Wt3  = Wt2 + 512 * 512;                     // [128][512]
    float* el = (float*)(Wt3 + 128 * 512);                      // N*8
    float* er = el + (size_t)N_NODES * 8;                       // N*8
    int* rowptr  = (int*)(er + (size_t)N_NODES * 8);            // N+1
    int* cursor  = rowptr + (N_NODES + 1);
    int* part    = cursor + N_NODES;
    int* csr_src = part + 256;                                  // E + 8 pad

    const dim3 blk(256);
    const int E = N_EDGES, N = N_NODES;
    const int nb = (N + SCAN_B - 1) / SCAN_B;
    const int gy = (N + 127) / 128;        // 391
    const int tiles = gy * 2;              // 782
    const int g256 = 8 * ((tiles + 7) / 8);  // 784

    hipMemsetAsync(cursor, 0, (size_t)N * 4, stream);
    prep_k<<<(X4_N + WTOT + E + 255) / 256, blk, 0, stream>>>(
        x, W1, W2, W3, Wr3, dst, xb, Wt1, Wt2, Wt3, cursor);
    scan_blocks<<<nb, SCAN_B, 0, stream>>>(cursor, rowptr, part, N);
    scan_part<<<1, SCAN_B, 0, stream>>>(part, nb);
    add_off<<<nb, blk, 0, stream>>>(rowptr, cursor, part, csr_src, N, E);
    scatter_k<<<(E + 255) / 256, blk, 0, stream>>>(src, dst, cursor, csr_src, E);

    // ================= layer 1 =================
    gemm256<8><<<g256, dim3(512), 0, stream>>>(
        xb, Wt1, fb, al1, ar1, el, er, N, 512, 256);
    gat_agg8<false><<<(N + 3) / 4, blk, 0, stream>>>(
        fb, el, er, rowptr, csr_src, nullptr, b1, h1b, N);

    // ================= layer 2 (identity residual = h1) =================
    gemm256<8><<<g256, dim3(512), 0, stream>>>(
        h1b, Wt2, fb, al2, ar2, el, er, N, 512, 512);
    gat_agg8<true><<<(N + 3) / 4, blk, 0, stream>>>(
        fb, el, er, rowptr, csr_src, h1b, b2, h2b, N);

    // ================= layer 3 (1 head, projected residual) =================
    gemm_mfma<1><<<gy, blk, 0, stream>>>(
        h2b, Wt3, f3r, al3, ar3, el, er, N, 128, 512);
    gat_agg1<<<(N + 3) / 4, blk, 0, stream>>>(
        f3r, el, er, rowptr, csr_src, b3, out, N);
}

// Round 9
// 335.239 us; speedup vs baseline: 1.0456x; 1.0456x over previous
//
#include <hip/hip_runtime.h>
#include <hip/hip_bf16.h>

#define N_NODES 50000
#define M_PAD 50048
#define N_EDGES 400000
#define SCAN_B 256

typedef __attribute__((ext_vector_type(8))) short short8;
typedef __attribute__((ext_vector_type(4))) float f32x4;

__device__ __forceinline__ unsigned short f2b(float f) {
    unsigned u = __float_as_uint(f);
    return (unsigned short)((u + 0x7fffu + ((u >> 16) & 1u)) >> 16);
}
__device__ __forceinline__ float blo(unsigned u) { return __uint_as_float(u << 16); }
__device__ __forceinline__ float bhi(unsigned u) { return __uint_as_float(u & 0xffff0000u); }

__device__ __forceinline__ void gload_lds16(const void* g, void* l) {
    __builtin_amdgcn_global_load_lds(
        (const __attribute__((address_space(1))) unsigned int*)g,
        (__attribute__((address_space(3))) unsigned int*)l, 16, 0, 0);
}

// ---------------- fused prep: x->bf16, weights->bf16 transposed, degree histogram ----------------
#define X4_N (N_NODES * 64)
#define W1_SZ (512 * 256)
#define W2_SZ (512 * 512)
#define W3_SZ (64 * 512)
#define WTOT (W1_SZ + W2_SZ + 2 * W3_SZ)
__global__ __launch_bounds__(256) void prep_k(const float* __restrict__ x,
                                              const float* __restrict__ W1,
                                              const float* __restrict__ W2,
                                              const float* __restrict__ W3,
                                              const float* __restrict__ Wr3,
                                              const int* __restrict__ dst,
                                              unsigned short* __restrict__ xb,
                                              unsigned short* __restrict__ Wt1,
                                              unsigned short* __restrict__ Wt2,
                                              unsigned short* __restrict__ Wt3,
                                              int* __restrict__ deg) {
    int i = blockIdx.x * blockDim.x + threadIdx.x;
    if (i < X4_N) {
        float4 v = *(const float4*)&x[(size_t)i * 4];
        unsigned short o[4] = {f2b(v.x), f2b(v.y), f2b(v.z), f2b(v.w)};
        *(ushort2*)&xb[(size_t)i * 4] = make_ushort2(o[0], o[1]);
        *(ushort2*)&xb[(size_t)i * 4 + 2] = make_ushort2(o[2], o[3]);
        return;
    }
    int o = i - X4_N;
    if (o < W1_SZ) {
        int n = o / 256, k = o % 256;
        Wt1[o] = f2b(W1[(size_t)k * 512 + n]);
    } else if (o < W1_SZ + W2_SZ) {
        int oo = o - W1_SZ;
        int n = oo / 512, k = oo % 512;
        Wt2[oo] = f2b(W2[(size_t)k * 512 + n]);
    } else if (o < W1_SZ + W2_SZ + W3_SZ) {
        int oo = o - W1_SZ - W2_SZ;
        int n = oo / 512, k = oo % 512;
        Wt3[oo] = f2b(W3[(size_t)k * 64 + n]);
    } else if (o < WTOT) {
        int oo = o - W1_SZ - W2_SZ - W3_SZ;
        int n = oo / 512, k = oo % 512;
        Wt3[W3_SZ + oo] = f2b(Wr3[(size_t)k * 64 + n]);
    } else {
        int e = o - WTOT;
        if (e < N_EDGES) atomicAdd(&deg[dst[e]], 1);
    }
}

// ---------------- bf16 MFMA GEMM, XCD-co-located row panels, fused el/er (round-7 config) ----------------
template <int H, int NBX, bool ELER>
__global__ __launch_bounds__(256, 2) void gemm_mfma(const unsigned short* __restrict__ A,
                                                    const unsigned short* __restrict__ Bt,
                                                    unsigned short* __restrict__ C,
                                                    const float* __restrict__ al,
                                                    const float* __restrict__ ar,
                                                    float* __restrict__ el,
                                                    float* __restrict__ er,
                                                    int M, int NN, int K) {
    const int nby = (M + 127) >> 7;
    int bid = blockIdx.x;
    int r, c;
    if (NBX == 4) {
        int full = nby & ~7;
        int nfull = full * 4;
        if (bid < nfull) {
            r = (bid >> 5) * 8 + (bid & 7);
            c = (bid >> 3) & 3;
        } else {
            int t = bid - nfull, rem = nby - full;
            r = full + t % rem;
            c = t / rem;
        }
    } else {
        r = bid;
        c = 0;
    }
    __shared__ unsigned short As[128 * 32];
    __shared__ unsigned short Bs[128 * 32];
    const int tid = threadIdx.x;
    const int w = tid >> 6, l = tid & 63;
    const int bm = r * 128, bn = c * 128;
    const int wr = w >> 1, wc = w & 1;
    const int rA = l >> 2;
    const int kA = (l & 3) * 8;
    const int fr = l & 15, fq = l >> 4;
    f32x4 acc[4][4] = {};

    for (int k0 = 0; k0 < K; k0 += 32) {
#pragma unroll
        for (int j = 0; j < 2; ++j) {
            int row = w * 32 + j * 16 + rA;
            gload_lds16(&A[(size_t)(bm + row) * K + k0 + kA], &As[(w * 2 + j) * 512]);
            gload_lds16(&Bt[(size_t)(bn + row) * K + k0 + kA], &Bs[(w * 2 + j) * 512]);
        }
        __syncthreads();
        short8 a[4], b[4];
#pragma unroll
        for (int m = 0; m < 4; ++m)
            a[m] = *(const short8*)&As[(wr * 64 + m * 16 + fr) * 32 + fq * 8];
#pragma unroll
        for (int n = 0; n < 4; ++n)
            b[n] = *(const short8*)&Bs[(wc * 64 + n * 16 + fr) * 32 + fq * 8];
#pragma unroll
        for (int m = 0; m < 4; ++m)
#pragma unroll
            for (int n = 0; n < 4; ++n)
                acc[m][n] = __builtin_amdgcn_mfma_f32_16x16x32_bf16(a[m], b[n], acc[m][n], 0, 0, 0);
        __syncthreads();
    }

    if (ELER) {
        const int head = (bn >> 6) + wc;
        if (head < H) {
            float alv[4], arv[4];
#pragma unroll
            for (int n = 0; n < 4; ++n) {
                alv[n] = al[head * 64 + n * 16 + fr];
                arv[n] = ar[head * 64 + n * 16 + fr];
            }
#pragma unroll
            for (int m = 0; m < 4; ++m) {
#pragma unroll
                for (int j = 0; j < 4; ++j) {
                    float pl = acc[m][0][j] * alv[0] + acc[m][1][j] * alv[1] +
                               acc[m][2][j] * alv[2] + acc[m][3][j] * alv[3];
                    float pr = acc[m][0][j] * arv[0] + acc[m][1][j] * arv[1] +
                               acc[m][2][j] * arv[2] + acc[m][3][j] * arv[3];
#pragma unroll
                    for (int off = 1; off < 16; off <<= 1) {
                        pl += __shfl_xor(pl, off);
                        pr += __shfl_xor(pr, off);
                    }
                    int rr = bm + wr * 64 + m * 16 + fq * 4 + j;
                    if (fr == 0 && rr < M) {
                        el[(size_t)rr * H + head] = pl;
                        er[(size_t)rr * H + head] = pr;
                    }
                }
            }
        }
    }

#pragma unroll
    for (int m = 0; m < 4; ++m) {
#pragma unroll
        for (int j = 0; j < 4; ++j) {
            int rr = bm + wr * 64 + m * 16 + fq * 4 + j;
            if (rr < M) {
#pragma unroll
                for (int n = 0; n < 4; ++n)
                    C[(size_t)rr * NN + bn + wc * 64 + n * 16 + fr] = f2b(acc[m][n][j]);
            }
        }
    }
}

// ---------------- CSR build ----------------
__global__ __launch_bounds__(SCAN_B) void scan_blocks(const int* __restrict__ in,
                                                      int* __restrict__ out,
                                                      int* __restrict__ part, int n) {
    __shared__ int tmp[SCAN_B];
    int t = threadIdx.x, g = blockIdx.x * SCAN_B + t;
    int v = (g < n) ? in[g] : 0;
    tmp[t] = v;
    __syncthreads();
    for (int off = 1; off < SCAN_B; off <<= 1) {
        int add = (t >= off) ? tmp[t - off] : 0;
        __syncthreads();
        tmp[t] += add;
        __syncthreads();
    }
    if (g < n) out[g] = tmp[t] - v;
    if (t == SCAN_B - 1) part[blockIdx.x] = tmp[t];
}

__global__ __launch_bounds__(SCAN_B) void scan_part(int* __restrict__ part, int n) {
    __shared__ int tmp[SCAN_B];
    int t = threadIdx.x;
    int v = (t < n) ? part[t] : 0;
    tmp[t] = v;
    __syncthreads();
    for (int off = 1; off < SCAN_B; off <<= 1) {
        int add = (t >= off) ? tmp[t - off] : 0;
        __syncthreads();
        tmp[t] += add;
        __syncthreads();
    }
    if (t < n) part[t] = tmp[t] - v;
}

__global__ __launch_bounds__(256) void add_off(int* __restrict__ rowptr,
                                               int* __restrict__ cursor,
                                               const int* __restrict__ part,
                                               int* __restrict__ csr_src,
                                               int n, int E) {
    int g = blockIdx.x * blockDim.x + threadIdx.x;
    if (g < n) {
        int v = rowptr[g] + part[g / SCAN_B];
        rowptr[g] = v;
        cursor[g] = v;
    }
    if (g == 0) rowptr[n] = E;
    if (g < 8) csr_src[E + g] = 0;   // pad: valid node id
}

__global__ __launch_bounds__(256) void scatter_k(const int* __restrict__ src,
                                                 const int* __restrict__ dst,
                                                 int* __restrict__ cursor,
                                                 int* __restrict__ csr_src, int E) {
    int e = blockIdx.x * blockDim.x + threadIdx.x;
    if (e < E) {
        int p = atomicAdd(&cursor[dst[e]], 1);
        csr_src[p] = src[e];
    }
}

// ---------------- fused GAT aggregation H=8: single pass, no-max softmax ----------------
template <bool HAS_INIT>
__global__ __launch_bounds__(256) void gat_agg8(const unsigned short* __restrict__ f,
                                                const float* __restrict__ el,
                                                const float* __restrict__ er,
                                                const int* __restrict__ rowptr,
                                                const int* __restrict__ csr_src,
                                                const unsigned short* __restrict__ init,
                                                const float* __restrict__ bias,
                                                unsigned short* __restrict__ outb, int N) {
    int w = (blockIdx.x * blockDim.x + threadIdx.x) >> 6;
    int lane = threadIdx.x & 63;
    if (w >= N) return;
    const int d = w;
    const int s0 = rowptr[d], s1 = rowptr[d + 1];
    const int hh = lane & 7;      // head for score lanes
    const int esub = lane >> 3;   // edge sub-index for score lanes
    const int myhead = lane >> 3; // head for gather lanes
    const int sl8 = lane * 8;
    const float erh = er[(size_t)d * 8 + hh];

    // single fused pass: gather + unnormalized exp weights (scores bounded -> exp safe)
    float sm = 0.f;
    float acc[8] = {};
    for (int ii = s0; ii < s1; ii += 8) {
        int snj[8];
#pragma unroll
        for (int j = 0; j < 8; ++j)
            snj[j] = csr_src[(ii + j < s1) ? (ii + j) : N_EDGES];
        uint4 qk[8];
#pragma unroll
        for (int j = 0; j < 8; ++j)
            qk[j] = *(const uint4*)&f[(size_t)snj[j] * 512 + sl8];
        bool valid = ii + esub < s1;
        float v = el[(size_t)snj[esub] * 8 + hh] + erh;
        v = v > 0.f ? v : 0.2f * v;
        float am = valid ? __expf(v) : 0.f;   // no max subtraction: |v| << 87
        sm += am;
#pragma unroll
        for (int j = 0; j < 8; ++j) {
            float alpha = __shfl(am, (j << 3) | myhead);
            acc[0] += blo(qk[j].x) * alpha;
            acc[1] += bhi(qk[j].x) * alpha;
            acc[2] += blo(qk[j].y) * alpha;
            acc[3] += bhi(qk[j].y) * alpha;
            acc[4] += blo(qk[j].z) * alpha;
            acc[5] += bhi(qk[j].z) * alpha;
            acc[6] += blo(qk[j].w) * alpha;
            acc[7] += bhi(qk[j].w) * alpha;
        }
    }

    // normalize
    sm += __shfl_xor(sm, 8);
    sm += __shfl_xor(sm, 16);
    sm += __shfl_xor(sm, 32);
    float smh = __shfl(sm, myhead);
    float inv = smh > 0.f ? 1.0f / smh : 0.f;
#pragma unroll
    for (int j = 0; j < 8; ++j) acc[j] *= inv;

    // epilogue
    const int sl = (lane & 7) * 8;
    float4 b0 = *(const float4*)&bias[myhead * 64 + sl];
    float4 b1 = *(const float4*)&bias[myhead * 64 + sl + 4];
    float bb[8] = {b0.x, b0.y, b0.z, b0.w, b1.x, b1.y, b1.z, b1.w};
    if (HAS_INIT) {
        uint4 iv = *(const uint4*)&init[(size_t)d * 512 + sl8];
        acc[0] += blo(iv.x); acc[1] += bhi(iv.x);
        acc[2] += blo(iv.y); acc[3] += bhi(iv.y);
        acc[4] += blo(iv.z); acc[5] += bhi(iv.z);
        acc[6] += blo(iv.w); acc[7] += bhi(iv.w);
    }
    unsigned short ob[8];
#pragma unroll
    for (int j = 0; j < 8; ++j) {
        float v = acc[j] + bb[j];
        v = v > 0.f ? v : __expf(v) - 1.f;
        ob[j] = f2b(v);
    }
    uint4 ov;
    ov.x = (unsigned)ob[0] | ((unsigned)ob[1] << 16);
    ov.y = (unsigned)ob[2] | ((unsigned)ob[3] << 16);
    ov.z = (unsigned)ob[4] | ((unsigned)ob[5] << 16);
    ov.w = (unsigned)ob[6] | ((unsigned)ob[7] << 16);
    *(uint4*)&outb[(size_t)d * 512 + sl8] = ov;
}

// ---------------- fused GAT aggregation H=1 (layer 3): single pass, no-max ----------------
__global__ __launch_bounds__(256) void gat_agg1(const unsigned short* __restrict__ f, // [*,128]
                                                const float* __restrict__ el,
                                                const float* __restrict__ er,
                                                const int* __restrict__ rowptr,
                                                const int* __restrict__ csr_src,
                                                const float* __restrict__ bias,
                                                float* __restrict__ outf, int N) {
    int w = (blockIdx.x * blockDim.x + threadIdx.x) >> 6;
    int lane = threadIdx.x & 63;
    if (w >= N) return;
    const int d = w;
    const int s0 = rowptr[d], s1 = rowptr[d + 1];
    const int esub = lane >> 3, sl = (lane & 7) * 8;
    const float erh = er[d];

    float sm = 0.f;
    float acc[8] = {};
    for (int ii = s0; ii < s1; ii += 8) {
        int i = ii + esub;
        bool valid = i < s1;
        int sn = csr_src[valid ? i : N_EDGES];
        uint4 pk = *(const uint4*)&f[(size_t)sn * 128 + sl];
        float v = el[sn] + erh;
        v = v > 0.f ? v : 0.2f * v;
        float am = valid ? __expf(v) : 0.f;
        sm += am;
        acc[0] += blo(pk.x) * am; acc[1] += bhi(pk.x) * am;
        acc[2] += blo(pk.y) * am; acc[3] += bhi(pk.y) * am;
        acc[4] += blo(pk.z) * am; acc[5] += bhi(pk.z) * am;
        acc[6] += blo(pk.w) * am; acc[7] += bhi(pk.w) * am;
    }

    sm += __shfl_xor(sm, 8);
    sm += __shfl_xor(sm, 16);
    sm += __shfl_xor(sm, 32);
#pragma unroll
    for (int off = 8; off < 64; off <<= 1)
#pragma unroll
        for (int j = 0; j < 8; ++j) acc[j] += __shfl_xor(acc[j], off);
    float inv = sm > 0.f ? 1.0f / sm : 0.f;

    if (esub == 0) {
        uint4 rv = *(const uint4*)&f[(size_t)d * 128 + 64 + sl];
        float rr[8] = {blo(rv.x), bhi(rv.x), blo(rv.y), bhi(rv.y),
                       blo(rv.z), bhi(rv.z), blo(rv.w), bhi(rv.w)};
#pragma unroll
        for (int j = 0; j < 8; ++j)
            outf[(size_t)d * 64 + sl + j] = acc[j] * inv + bias[sl + j] + rr[j];
    }
}

extern "C" void kernel_launch(void* const* d_in, const int* in_sizes, int n_in,
                              void* d_out, int out_size, void* d_ws, size_t ws_size,
                              hipStream_t stream) {
    const float* x   = (const float*)d_in[0];
    const int*   src = (const int*)d_in[1];
    const int*   dst = (const int*)d_in[2];
    const float* W1  = (const float*)d_in[3];
    const float* al1 = (const float*)d_in[4];
    const float* ar1 = (const float*)d_in[5];
    const float* b1  = (const float*)d_in[6];
    const float* W2  = (const float*)d_in[7];
    const float* al2 = (const float*)d_in[8];
    const float* ar2 = (const float*)d_in[9];
    const float* b2  = (const float*)d_in[10];
    const float* W3  = (const float*)d_in[11];
    const float* al3 = (const float*)d_in[12];
    const float* ar3 = (const float*)d_in[13];
    const float* b3  = (const float*)d_in[14];
    const float* Wr3 = (const float*)d_in[15];
    float* out = (float*)d_out;

    unsigned short* xb   = (unsigned short*)d_ws;               // [M_PAD][256]
    unsigned short* fb   = xb + (size_t)M_PAD * 256;            // [M_PAD][512]
    unsigned short* h1b  = fb + (size_t)M_PAD * 512;            // [M_PAD][512]
    unsigned short* h2b  = h1b + (size_t)M_PAD * 512;           // [M_PAD][512]
    unsigned short* f3r  = h2b + (size_t)M_PAD * 512;           // [M_PAD][128]
    unsigned short* Wt1  = f3r + (size_t)M_PAD * 128;           // [512][256]
    unsigned short* Wt2  = Wt1 + 512 * 256;                     // [512][512]
    unsigned short* Wt3  = Wt2 + 512 * 512;                     // [128][512]
    float* el = (float*)(Wt3 + 128 * 512);                      // N*8
    float* er = el + (size_t)N_NODES * 8;                       // N*8
    int* rowptr  = (int*)(er + (size_t)N_NODES * 8);            // N+1
    int* cursor  = rowptr + (N_NODES + 1);
    int* part    = cursor + N_NODES;
    int* csr_src = part + 256;                                  // E + 8 pad

    const dim3 blk(256);
    const int E = N_EDGES, N = N_NODES;
    const int nb = (N + SCAN_B - 1) / SCAN_B;
    const int gy = (N + 127) / 128;   // 391

    hipMemsetAsync(cursor, 0, (size_t)N * 4, stream);
    prep_k<<<(X4_N + WTOT + E + 255) / 256, blk, 0, stream>>>(
        x, W1, W2, W3, Wr3, dst, xb, Wt1, Wt2, Wt3, cursor);
    scan_blocks<<<nb, SCAN_B, 0, stream>>>(cursor, rowptr, part, N);
    scan_part<<<1, SCAN_B, 0, stream>>>(part, nb);
    add_off<<<nb, blk, 0, stream>>>(rowptr, cursor, part, csr_src, N, E);
    scatter_k<<<(E + 255) / 256, blk, 0, stream>>>(src, dst, cursor, csr_src, E);

    // ================= layer 1 =================
    gemm_mfma<8, 4, true><<<4 * gy, blk, 0, stream>>>(
        xb, Wt1, fb, al1, ar1, el, er, N, 512, 256);
    gat_agg8<false><<<(N + 3) / 4, blk, 0, stream>>>(
        fb, el, er, rowptr, csr_src, nullptr, b1, h1b, N);

    // ================= layer 2 (identity residual = h1) =================
    gemm_mfma<8, 4, true><<<4 * gy, blk, 0, stream>>>(
        h1b, Wt2, fb, al2, ar2, el, er, N, 512, 512);
    gat_agg8<true><<<(N + 3) / 4, blk, 0, stream>>>(
        fb, el, er, rowptr, csr_src, h1b, b2, h2b, N);

    // ================= layer 3 (1 head, projected residual) =================
    gemm_mfma<1, 1, true><<<gy, blk, 0, stream>>>(
        h2b, Wt3, f3r, al3, ar3, el, er, N, 128, 512);
    gat_agg1<<<(N + 3) / 4, blk, 0, stream>>>(
        f3r, el, er, rowptr, csr_src, b3, out, N);
}